// Round 4
// baseline (389.720 us; speedup 1.0000x reference)
//
#include <hip/hip_runtime.h>
#include <math.h>

#define NS 4096
#define NV 65536
#define DDIM 128
#define EPSV 1e-6f
#define NCHUNK 16
#define TILES_PER_CHUNK 32
#define FLTMAX 3.402823466e+38f
#define IMAX 0x7fffffff

// ws float offsets
#define XSQ_F   131072
#define XSUM_F  135168
#define PART_F  139264              // 4096 samples x 16 chunks x float4
#define WS_TILED_BYTE 1605632      // tiled V region (bytes), 256B aligned
#define TILE_BYTES 65536            // 8 s x 2 split x 2 q x 128 m x 16B
#define TILE_STRIDE 66560           // + 1KB cj slot (512B cj + pad)
#define BUFB 66560                  // LDS buffer stride (double-buffered)

typedef __attribute__((ext_vector_type(8)))  __bf16        bf16x8;
typedef __attribute__((ext_vector_type(8)))  unsigned short ush8;
typedef __attribute__((ext_vector_type(16))) float          f32x16;

typedef const __attribute__((address_space(1))) unsigned int* gp_t;
typedef __attribute__((address_space(3))) unsigned int*       lp_t;

__device__ __forceinline__ void async_cp16(const void* g, void* l) {
    __builtin_amdgcn_global_load_lds((gp_t)g, (lp_t)l, 16, 0, 0);
}

__device__ __forceinline__ unsigned short f2bf(float x) {
    unsigned u = __builtin_bit_cast(unsigned, x);
    u += 0x7FFFu + ((u >> 16) & 1u);      // RNE
    return (unsigned short)(u >> 16);
}
__device__ __forceinline__ float bf2f(unsigned short h) {
    unsigned u = ((unsigned)h) << 16;
    return __builtin_bit_cast(float, u);
}

__device__ __forceinline__ void merge2t(float& d1, int& i1, float& d2, int& i2,
                                        float d, int i) {
    bool b1 = (d < d1) || (d == d1 && i < i1);
    bool b2 = (d < d2) || (d == d2 && i < i2);
    if (b1) { d2 = d1; i2 = i1; d1 = d; i1 = i; }
    else if (b2) { d2 = d; i2 = i; }
}

// ---- K1: row stats; V rows -> cj written straight into tile cj slots ----
__global__ void vq_precompute(const float* __restrict__ samples,
                              const float* __restrict__ V,
                              float* __restrict__ ws_f, char* __restrict__ ws_b) {
    const int wave = threadIdx.x >> 6;
    const int lane = threadIdx.x & 63;
    int row = blockIdx.x * 4 + wave;
    const float* src;
    bool isV = (row < NV);
    int r = isV ? row : row - NV;
    if (!isV && r >= NS) return;
    src = (isV ? V : samples) + (size_t)r * DDIM;
    float2 v = ((const float2*)src)[lane];
    float s = v.x + v.y;
    float q = v.x * v.x + v.y * v.y;
    #pragma unroll
    for (int off = 32; off >= 1; off >>= 1) {
        s += __shfl_xor(s, off);
        q += __shfl_xor(q, off);
    }
    if (lane == 0) {
        if (isV) {
            int tile = r >> 7, m = r & 127;
            *(float*)(ws_b + WS_TILED_BYTE + (size_t)tile * TILE_STRIDE + TILE_BYTES + m * 4)
                = q - 2.0f * EPSV * s;
        } else {
            ws_f[XSQ_F + r] = q;
            ws_f[XSUM_F + r] = s;
        }
    }
}

// ---- K2: V -> tiled bf16 hi/lo fragments (coalesced 16B writes) ----
__global__ void vq_convertV(const float* __restrict__ V, char* __restrict__ ws) {
    const int tile = blockIdx.x;
    const int tid = threadIdx.x;
    const int q = tid >> 7, row = tid & 127;
    char* dst = ws + WS_TILED_BYTE + (size_t)tile * TILE_STRIDE;
    const float4* v4 = (const float4*)(V + (size_t)(tile * 128 + row) * DDIM);
    #pragma unroll
    for (int s = 0; s < 8; s++) {
        float4 g0 = v4[s * 4 + q * 2];
        float4 g1 = v4[s * 4 + q * 2 + 1];
        float xs[8] = {g0.x, g0.y, g0.z, g0.w, g1.x, g1.y, g1.z, g1.w};
        ush8 h, l;
        #pragma unroll
        for (int e = 0; e < 8; e++) {
            unsigned short hh = f2bf(xs[e]);
            h[e] = hh;
            l[e] = f2bf(xs[e] - bf2f(hh));
        }
        *(ush8*)(dst + ((((s * 2 + 0) * 2 + q) * 128) + row) * 16) = h;
        *(ush8*)(dst + ((((s * 2 + 1) * 2 + q) * 128) + row) * 16) = l;
    }
}

// ---- K3: MFMA GEMM + fused top-2 ----
// 512 threads = 8 waves; block tile: 128 codes (M) x 256 samples (N)
// wave (wy,wx): codes [wy*64,+64), samples [wx*64,+64) as two 32-col blocks.
// NOTE: two waves (wy=0,1) cover the SAME samples -> cross-wy LDS merge at end.
__global__ __launch_bounds__(512, 2)
void vq_gemm_topk(const float* __restrict__ samples, char* __restrict__ ws) {
    __shared__ __align__(16) char lds[2 * BUFB];
    const int tid = threadIdx.x;
    const int w = tid >> 6, lane = tid & 63;
    const int l31 = lane & 31, q = lane >> 5;
    const int wy = w >> 2, wx = w & 3;
    const int st = blockIdx.x;       // sample tile 0..15 (256 samples each)
    const int chunk = blockIdx.y;    // 0..15

    // B fragments: samples scaled by -2 (exact), split hi/lo, in VGPRs
    ush8 bh[2][8], bl[2][8];
    const float4* s4 = (const float4*)samples;
    #pragma unroll
    for (int nb = 0; nb < 2; nb++) {
        const int nrow = st * 256 + wx * 64 + nb * 32 + l31;
        #pragma unroll
        for (int s = 0; s < 8; s++) {
            float4 x0 = s4[(size_t)nrow * 32 + s * 4 + q * 2];
            float4 x1 = s4[(size_t)nrow * 32 + s * 4 + q * 2 + 1];
            float xs[8] = {x0.x, x0.y, x0.z, x0.w, x1.x, x1.y, x1.z, x1.w};
            #pragma unroll
            for (int j = 0; j < 8; j++) {
                float y = -2.0f * xs[j];
                unsigned short hh = f2bf(y);
                bh[nb][s][j] = hh;
                bl[nb][s][j] = f2bf(y - bf2f(hh));
            }
        }
    }

    float d1[2] = {FLTMAX, FLTMAX}, d2[2] = {FLTMAX, FLTMAX};
    int i1[2] = {IMAX, IMAX}, i2[2] = {IMAX, IMAX};

    const char* tile0 = ws + WS_TILED_BYTE + (size_t)(chunk * TILES_PER_CHUNK) * TILE_STRIDE;

    auto stage = [&](int it) {
        const char* src = tile0 + (size_t)it * TILE_STRIDE;
        char* dstb = lds + (it & 1) * BUFB;
        #pragma unroll
        for (int i = 0; i < 8; i++) {
            int off = (i * 512 + tid) * 16;
            async_cp16(src + off, dstb + off);
        }
        if (tid < 32) {
            int off = TILE_BYTES + tid * 16;
            async_cp16(src + off, dstb + off);
        }
    };

    stage(0);
    __syncthreads();                 // vmcnt(0) drain: buf0 ready

    for (int it = 0; it < TILES_PER_CHUNK; it++) {
        if (it + 1 < TILES_PER_CHUNK) stage(it + 1);   // prefetch overlaps compute
        const char* buf = lds + (it & 1) * BUFB;

        f32x16 acc[4];
        #pragma unroll
        for (int a = 0; a < 4; a++)
            #pragma unroll
            for (int r = 0; r < 16; r++) acc[a][r] = 0.0f;

        #pragma unroll
        for (int s = 0; s < 8; s++) {
            #pragma unroll
            for (int mi = 0; mi < 2; mi++) {
                bf16x8 ah = *(const bf16x8*)(buf + (size_t)((((s * 2 + 0) * 2 + q) * 128) + wy * 64 + mi * 32 + l31) * 16);
                bf16x8 al = *(const bf16x8*)(buf + (size_t)((((s * 2 + 1) * 2 + q) * 128) + wy * 64 + mi * 32 + l31) * 16);
                #pragma unroll
                for (int nb = 0; nb < 2; nb++) {
                    bf16x8 bhs = __builtin_bit_cast(bf16x8, bh[nb][s]);
                    bf16x8 bls = __builtin_bit_cast(bf16x8, bl[nb][s]);
                    acc[mi * 2 + nb] = __builtin_amdgcn_mfma_f32_32x32x16_bf16(ah, bhs, acc[mi * 2 + nb], 0, 0, 0);
                    acc[mi * 2 + nb] = __builtin_amdgcn_mfma_f32_32x32x16_bf16(ah, bls, acc[mi * 2 + nb], 0, 0, 0);
                    acc[mi * 2 + nb] = __builtin_amdgcn_mfma_f32_32x32x16_bf16(al, bhs, acc[mi * 2 + nb], 0, 0, 0);
                }
            }
        }

        // epilogue: v = cj - 2*dot ; ballot-guarded top-2 (rare path)
        const int ibase = chunk * 4096 + it * 128 + wy * 64 + 4 * q;
        #pragma unroll
        for (int mi = 0; mi < 2; mi++) {
            #pragma unroll
            for (int g = 0; g < 4; g++) {
                float4 cj = *(const float4*)(buf + TILE_BYTES + (size_t)(wy * 64 + mi * 32 + g * 8 + 4 * q) * 4);
                float cje[4] = {cj.x, cj.y, cj.z, cj.w};
                #pragma unroll
                for (int nb = 0; nb < 2; nb++) {
                    #pragma unroll
                    for (int e = 0; e < 4; e++) {
                        float v = acc[mi * 2 + nb][g * 4 + e] + cje[e];
                        int idx = ibase + mi * 32 + g * 8 + e;
                        if (__builtin_expect(__ballot(v < d2[nb]) != 0, 0)) {
                            bool c1 = v < d1[nb];
                            float t2 = c1 ? d1[nb] : v;
                            int   j2 = c1 ? i1[nb] : idx;
                            bool c2 = v < d2[nb];
                            d2[nb] = c2 ? t2 : d2[nb];
                            i2[nb] = c2 ? j2 : i2[nb];
                            d1[nb] = c1 ? v  : d1[nb];
                            i1[nb] = c1 ? idx : i1[nb];
                        }
                    }
                }
            }
        }
        __syncthreads();   // waits prefetch (overlapped) + readers of this buf
    }

    // (1) merge the two q-lanes sharing each sample column (within wave)
    #pragma unroll
    for (int nb = 0; nb < 2; nb++) {
        float od1 = __shfl_xor(d1[nb], 32), od2 = __shfl_xor(d2[nb], 32);
        int   oi1 = __shfl_xor(i1[nb], 32), oi2 = __shfl_xor(i2[nb], 32);
        merge2t(d1[nb], i1[nb], d2[nb], i2[nb], od1, oi1);
        merge2t(d1[nb], i1[nb], d2[nb], i2[nb], od2, oi2);
    }

    // (2) cross-wy merge: wy=1 publishes via LDS (buffers are dead now), wy=0 merges.
    float4* mscratch = (float4*)lds;   // 256 samples x 16B = 4 KB
    if (wy == 1 && q == 0) {
        #pragma unroll
        for (int nb = 0; nb < 2; nb++) {
            int sl = wx * 64 + nb * 32 + l31;
            mscratch[sl] = make_float4(d1[nb], d2[nb], (float)i1[nb], (float)i2[nb]);
        }
    }
    __syncthreads();
    if (wy == 0 && q == 0) {
        float4* part = (float4*)((float*)ws + PART_F);
        #pragma unroll
        for (int nb = 0; nb < 2; nb++) {
            int sl = wx * 64 + nb * 32 + l31;
            float4 o = mscratch[sl];
            merge2t(d1[nb], i1[nb], d2[nb], i2[nb], o.x, (int)o.z);
            merge2t(d1[nb], i1[nb], d2[nb], i2[nb], o.y, (int)o.w);
            int sample = st * 256 + sl;
            part[(size_t)sample * NCHUNK + chunk] =
                make_float4(d1[nb], d2[nb], (float)i1[nb], (float)i2[nb]);
        }
    }
}

// ---- K4: merge chunk partials, final outputs ----
__global__ void vq_reduce(const float* __restrict__ ws_f, float* __restrict__ out) {
    int m = blockIdx.x * 256 + threadIdx.x;
    if (m >= NS) return;
    const float4* part = (const float4*)(ws_f + PART_F);
    float d1 = FLTMAX, d2 = FLTMAX;
    int i1 = IMAX, i2 = IMAX;
    for (int c = 0; c < NCHUNK; c++) {
        float4 p = part[(size_t)m * NCHUNK + c];
        merge2t(d1, i1, d2, i2, p.x, (int)p.z);
        merge2t(d1, i1, d2, i2, p.y, (int)p.w);
    }
    float ci = ws_f[XSQ_F + m] + 2.0f * EPSV * ws_f[XSUM_F + m] + (float)DDIM * EPSV * EPSV;
    float sq = fmaxf(ci + d1, 0.0f);
    out[m]          = (float)i1;
    out[NS + m]     = (float)i2;
    out[2 * NS + m] = expf(-sqrtf(sq));
}

extern "C" void kernel_launch(void* const* d_in, const int* in_sizes, int n_in,
                              void* d_out, int out_size, void* d_ws, size_t ws_size,
                              hipStream_t stream) {
    (void)in_sizes; (void)n_in; (void)out_size; (void)ws_size;
    const float* samples = (const float*)d_in[0];
    const float* V = (const float*)d_in[1];
    float* out = (float*)d_out;
    float* ws_f = (float*)d_ws;
    char*  ws_b = (char*)d_ws;

    vq_precompute<<<dim3((NV + NS) / 4), 256, 0, stream>>>(samples, V, ws_f, ws_b);
    vq_convertV<<<dim3(NV / 128), 256, 0, stream>>>(V, ws_b);
    vq_gemm_topk<<<dim3(NS / 256, NCHUNK), 512, 0, stream>>>(samples, ws_b);
    vq_reduce<<<dim3(NS / 256), 256, 0, stream>>>(ws_f, out);
}

// Round 5
// 365.123 us; speedup vs baseline: 1.0674x; 1.0674x over previous
//
#include <hip/hip_runtime.h>
#include <math.h>

#define NS 4096
#define NV 65536
#define DDIM 128
#define EPSV 1e-6f
#define NCHUNK 16
#define TILES_PER_CHUNK 32
#define FLTMAX 3.402823466e+38f
#define IMAX 0x7fffffff

// ws float offsets
#define XSQ_F   131072
#define XSUM_F  135168
#define PART_F  139264              // 4096 samples x 16 chunks x float4
#define WS_TILED_BYTE 1605632      // tiled V region (bytes), 256B aligned
#define TILE_BYTES 65536            // 8 s x 2 split x 2 q x 128 m x 16B
#define TILE_STRIDE 66560           // + 1KB cj slot (512B cj + pad)
#define BUFB 66560

typedef __attribute__((ext_vector_type(8)))  __bf16        bf16x8;
typedef __attribute__((ext_vector_type(8)))  unsigned short ush8;
typedef __attribute__((ext_vector_type(16))) float          f32x16;

typedef const __attribute__((address_space(1))) unsigned int* gp_t;
typedef __attribute__((address_space(3))) unsigned int*       lp_t;

__device__ __forceinline__ void async_cp16(const void* g, void* l) {
    __builtin_amdgcn_global_load_lds((gp_t)g, (lp_t)l, 16, 0, 0);
}

__device__ __forceinline__ unsigned short f2bf(float x) {
    unsigned u = __builtin_bit_cast(unsigned, x);
    u += 0x7FFFu + ((u >> 16) & 1u);      // RNE
    return (unsigned short)(u >> 16);
}
__device__ __forceinline__ float bf2f(unsigned short h) {
    unsigned u = ((unsigned)h) << 16;
    return __builtin_bit_cast(float, u);
}

__device__ __forceinline__ void merge2t(float& d1, int& i1, float& d2, int& i2,
                                        float d, int i) {
    bool b1 = (d < d1) || (d == d1 && i < i1);
    bool b2 = (d < d2) || (d == d2 && i < i2);
    if (b1) { d2 = d1; i2 = i1; d1 = d; i1 = i; }
    else if (b2) { d2 = d; i2 = i; }
}

// ---- K1: sample row stats only ----
__global__ void vq_xstats(const float* __restrict__ samples, float* __restrict__ ws_f) {
    const int wave = threadIdx.x >> 6;
    const int lane = threadIdx.x & 63;
    int r = blockIdx.x * 4 + wave;
    if (r >= NS) return;
    float2 v = ((const float2*)(samples + (size_t)r * DDIM))[lane];
    float s = v.x + v.y;
    float q = v.x * v.x + v.y * v.y;
    #pragma unroll
    for (int off = 32; off >= 1; off >>= 1) {
        s += __shfl_xor(s, off);
        q += __shfl_xor(q, off);
    }
    if (lane == 0) { ws_f[XSQ_F + r] = q; ws_f[XSUM_F + r] = s; }
}

// ---- K2: V -> tiled bf16 hi/lo fragments + fused cj (single pass over V) ----
__global__ void vq_convertV(const float* __restrict__ V, char* __restrict__ ws) {
    const int tile = blockIdx.x;
    const int tid = threadIdx.x;
    const int q = tid & 1, rl = tid >> 1;          // lane pairs share a row
    char* dst = ws + WS_TILED_BYTE + (size_t)tile * TILE_STRIDE;
    const float4* v4 = (const float4*)(V + (size_t)(tile * 128 + rl) * DDIM);
    float sum = 0.0f, sq = 0.0f;
    #pragma unroll
    for (int s = 0; s < 8; s++) {
        float4 g0 = v4[s * 4 + q * 2];
        float4 g1 = v4[s * 4 + q * 2 + 1];
        float xs[8] = {g0.x, g0.y, g0.z, g0.w, g1.x, g1.y, g1.z, g1.w};
        ush8 h, l;
        #pragma unroll
        for (int e = 0; e < 8; e++) {
            sum += xs[e];
            sq  += xs[e] * xs[e];
            unsigned short hh = f2bf(xs[e]);
            h[e] = hh;
            l[e] = f2bf(xs[e] - bf2f(hh));
        }
        *(ush8*)(dst + ((((s * 2 + 0) * 2 + q) * 128) + rl) * 16) = h;
        *(ush8*)(dst + ((((s * 2 + 1) * 2 + q) * 128) + rl) * 16) = l;
    }
    sum += __shfl_xor(sum, 1);
    sq  += __shfl_xor(sq, 1);
    if (q == 0)
        *(float*)(dst + TILE_BYTES + rl * 4) = sq - 2.0f * EPSV * sum;
}

// ---- K3: MFMA GEMM + fused top-2 ----
// 256 threads = 4 waves (wy,wx in {0,1}); block tile: 128 codes x 128 samples.
// wave: codes [wy*64,+64), samples [wx*64,+64) as two 32-col blocks.
// Single-buffered LDS (66 KB) -> 2 blocks/CU; inter-block overlap hides barriers.
__global__ __launch_bounds__(256, 2)
void vq_gemm_topk(const float* __restrict__ samples, char* __restrict__ ws) {
    __shared__ __align__(16) char lds[BUFB];
    const int tid = threadIdx.x;
    const int w = tid >> 6, lane = tid & 63;
    const int l31 = lane & 31, q = lane >> 5;
    const int wy = w >> 1, wx = w & 1;
    const int st = blockIdx.x;       // sample tile 0..31 (128 samples each)
    const int chunk = blockIdx.y;    // 0..15

    // B fragments: samples scaled by -2 (exact), split hi/lo, in VGPRs
    ush8 bh[2][8], bl[2][8];
    const float4* s4 = (const float4*)samples;
    #pragma unroll
    for (int nb = 0; nb < 2; nb++) {
        const int nrow = st * 128 + wx * 64 + nb * 32 + l31;
        #pragma unroll
        for (int s = 0; s < 8; s++) {
            float4 x0 = s4[(size_t)nrow * 32 + s * 4 + q * 2];
            float4 x1 = s4[(size_t)nrow * 32 + s * 4 + q * 2 + 1];
            float xs[8] = {x0.x, x0.y, x0.z, x0.w, x1.x, x1.y, x1.z, x1.w};
            #pragma unroll
            for (int j = 0; j < 8; j++) {
                float y = -2.0f * xs[j];
                unsigned short hh = f2bf(y);
                bh[nb][s][j] = hh;
                bl[nb][s][j] = f2bf(y - bf2f(hh));
            }
        }
    }

    float d1[2] = {FLTMAX, FLTMAX}, d2[2] = {FLTMAX, FLTMAX};
    int i1[2] = {IMAX, IMAX}, i2[2] = {IMAX, IMAX};

    const char* tile0 = ws + WS_TILED_BYTE + (size_t)(chunk * TILES_PER_CHUNK) * TILE_STRIDE;

    for (int it = 0; it < TILES_PER_CHUNK; it++) {
        const char* src = tile0 + (size_t)it * TILE_STRIDE;
        #pragma unroll
        for (int i = 0; i < 16; i++) {
            int off = (i * 256 + tid) * 16;
            async_cp16(src + off, lds + off);
        }
        if (tid < 64) {
            int off = TILE_BYTES + tid * 16;
            async_cp16(src + off, lds + off);
        }
        __syncthreads();

        f32x16 acc[4];
        #pragma unroll
        for (int a = 0; a < 4; a++)
            #pragma unroll
            for (int r = 0; r < 16; r++) acc[a][r] = 0.0f;

        #pragma unroll
        for (int s = 0; s < 8; s++) {
            #pragma unroll
            for (int mi = 0; mi < 2; mi++) {
                bf16x8 ah = *(const bf16x8*)(lds + (size_t)((((s * 2 + 0) * 2 + q) * 128) + wy * 64 + mi * 32 + l31) * 16);
                bf16x8 al = *(const bf16x8*)(lds + (size_t)((((s * 2 + 1) * 2 + q) * 128) + wy * 64 + mi * 32 + l31) * 16);
                #pragma unroll
                for (int nb = 0; nb < 2; nb++) {
                    bf16x8 bhs = __builtin_bit_cast(bf16x8, bh[nb][s]);
                    bf16x8 bls = __builtin_bit_cast(bf16x8, bl[nb][s]);
                    acc[mi * 2 + nb] = __builtin_amdgcn_mfma_f32_32x32x16_bf16(ah, bhs, acc[mi * 2 + nb], 0, 0, 0);
                    acc[mi * 2 + nb] = __builtin_amdgcn_mfma_f32_32x32x16_bf16(ah, bls, acc[mi * 2 + nb], 0, 0, 0);
                    acc[mi * 2 + nb] = __builtin_amdgcn_mfma_f32_32x32x16_bf16(al, bhs, acc[mi * 2 + nb], 0, 0, 0);
                }
            }
        }

        // epilogue: v = cj - 2*dot ; ballot-guarded top-2 (rare path)
        const int ibase = chunk * 4096 + it * 128 + wy * 64 + 4 * q;
        #pragma unroll
        for (int mi = 0; mi < 2; mi++) {
            #pragma unroll
            for (int g = 0; g < 4; g++) {
                float4 cj = *(const float4*)(lds + TILE_BYTES + (size_t)(wy * 64 + mi * 32 + g * 8 + 4 * q) * 4);
                float cje[4] = {cj.x, cj.y, cj.z, cj.w};
                #pragma unroll
                for (int nb = 0; nb < 2; nb++) {
                    #pragma unroll
                    for (int e = 0; e < 4; e++) {
                        float v = acc[mi * 2 + nb][g * 4 + e] + cje[e];
                        int idx = ibase + mi * 32 + g * 8 + e;
                        if (__builtin_expect(__ballot(v < d2[nb]) != 0, 0)) {
                            bool c1 = v < d1[nb];
                            float t2 = c1 ? d1[nb] : v;
                            int   j2 = c1 ? i1[nb] : idx;
                            bool c2 = v < d2[nb];
                            d2[nb] = c2 ? t2 : d2[nb];
                            i2[nb] = c2 ? j2 : i2[nb];
                            d1[nb] = c1 ? v  : d1[nb];
                            i1[nb] = c1 ? idx : i1[nb];
                        }
                    }
                }
            }
        }
        __syncthreads();   // all reads of lds done before next stage
    }

    // (1) q-lane merge (within wave)
    #pragma unroll
    for (int nb = 0; nb < 2; nb++) {
        float od1 = __shfl_xor(d1[nb], 32), od2 = __shfl_xor(d2[nb], 32);
        int   oi1 = __shfl_xor(i1[nb], 32), oi2 = __shfl_xor(i2[nb], 32);
        merge2t(d1[nb], i1[nb], d2[nb], i2[nb], od1, oi1);
        merge2t(d1[nb], i1[nb], d2[nb], i2[nb], od2, oi2);
    }

    // (2) cross-wy merge via LDS scratch (tile buffer is dead now)
    float4* mscratch = (float4*)lds;   // 128 samples x 16B = 2 KB
    if (wy == 1 && q == 0) {
        #pragma unroll
        for (int nb = 0; nb < 2; nb++) {
            int sl = wx * 64 + nb * 32 + l31;
            mscratch[sl] = make_float4(d1[nb], d2[nb], (float)i1[nb], (float)i2[nb]);
        }
    }
    __syncthreads();
    if (wy == 0 && q == 0) {
        float4* part = (float4*)((float*)ws + PART_F);
        #pragma unroll
        for (int nb = 0; nb < 2; nb++) {
            int sl = wx * 64 + nb * 32 + l31;
            float4 o = mscratch[sl];
            merge2t(d1[nb], i1[nb], d2[nb], i2[nb], o.x, (int)o.z);
            merge2t(d1[nb], i1[nb], d2[nb], i2[nb], o.y, (int)o.w);
            int sample = st * 128 + sl;
            part[(size_t)sample * NCHUNK + chunk] =
                make_float4(d1[nb], d2[nb], (float)i1[nb], (float)i2[nb]);
        }
    }
}

// ---- K4: merge chunk partials, final outputs ----
__global__ void vq_reduce(const float* __restrict__ ws_f, float* __restrict__ out) {
    int m = blockIdx.x * 256 + threadIdx.x;
    if (m >= NS) return;
    const float4* part = (const float4*)(ws_f + PART_F);
    float d1 = FLTMAX, d2 = FLTMAX;
    int i1 = IMAX, i2 = IMAX;
    for (int c = 0; c < NCHUNK; c++) {
        float4 p = part[(size_t)m * NCHUNK + c];
        merge2t(d1, i1, d2, i2, p.x, (int)p.z);
        merge2t(d1, i1, d2, i2, p.y, (int)p.w);
    }
    float ci = ws_f[XSQ_F + m] + 2.0f * EPSV * ws_f[XSUM_F + m] + (float)DDIM * EPSV * EPSV;
    float sq = fmaxf(ci + d1, 0.0f);
    out[m]          = (float)i1;
    out[NS + m]     = (float)i2;
    out[2 * NS + m] = expf(-sqrtf(sq));
}

extern "C" void kernel_launch(void* const* d_in, const int* in_sizes, int n_in,
                              void* d_out, int out_size, void* d_ws, size_t ws_size,
                              hipStream_t stream) {
    (void)in_sizes; (void)n_in; (void)out_size; (void)ws_size;
    const float* samples = (const float*)d_in[0];
    const float* V = (const float*)d_in[1];
    float* out = (float*)d_out;
    float* ws_f = (float*)d_ws;
    char*  ws_b = (char*)d_ws;

    vq_xstats<<<dim3(NS / 4), 256, 0, stream>>>(samples, ws_f);
    vq_convertV<<<dim3(NV / 128), 256, 0, stream>>>(V, ws_b);
    vq_gemm_topk<<<dim3(NS / 128, NCHUNK), 256, 0, stream>>>(samples, ws_b);
    vq_reduce<<<dim3(NS / 256), 256, 0, stream>>>(ws_f, out);
}